// Round 11
// baseline (333.308 us; speedup 1.0000x reference)
//
#include <hip/hip_runtime.h>

typedef short s8v __attribute__((ext_vector_type(8)));
typedef short s4v __attribute__((ext_vector_type(4)));
typedef unsigned u4v __attribute__((ext_vector_type(4)));
typedef float f4v __attribute__((ext_vector_type(4)));

typedef const __attribute__((address_space(1))) char* gp1_t;
typedef __attribute__((address_space(3))) char* lp3_t;

__device__ __forceinline__ float bf2f(short s) {
    union { unsigned u; float f; } c;
    c.u = ((unsigned)(unsigned short)s) << 16;
    return c.f;
}
__device__ __forceinline__ short f2bf(float f) {
    union { float f; unsigned u; } c; c.f = f;
    unsigned r = (c.u + 0x7FFFu + ((c.u >> 16) & 1u)) >> 16;
    return (short)r;
}
__device__ __forceinline__ unsigned cvt_pk_bf16(float a, float b) {
    unsigned r;
    asm("v_cvt_pk_bf16_f32 %0, %1, %2" : "=v"(r) : "v"(a), "v"(b));
    return r;
}
__device__ __forceinline__ s8v cvt8(const float* __restrict__ p) {
    f4v a = *(const f4v*)p;
    f4v b = *(const f4v*)(p + 4);
    s8v r;
    r[0] = f2bf(a[0]); r[1] = f2bf(a[1]); r[2] = f2bf(a[2]); r[3] = f2bf(a[3]);
    r[4] = f2bf(b[0]); r[5] = f2bf(b[1]); r[6] = f2bf(b[2]); r[7] = f2bf(b[3]);
    return r;
}

// ======================= FAST PATH (ws >= 64 MiB) =======================

// Merged preprocessing: blocks [0,2560) do the W transposes (region table),
// blocks [2560,6656) do the x fp32->bf16 copy. One launch replaces five.
__global__ __launch_bounds__(256) void prep(const float* __restrict__ x,
                                            const float* __restrict__ Wq,
                                            const float* __restrict__ Wk,
                                            const float* __restrict__ Wv,
                                            const float* __restrict__ Wo,
                                            short* __restrict__ xb,
                                            short* __restrict__ Wqkvt,
                                            short* __restrict__ Wot) {
    __shared__ __align__(16) short tile[64 * 72];
    int id = blockIdx.x;
    if (id >= 2560) {
        long i = ((long)(id - 2560) * 256 + threadIdx.x) * 8;
        *(s8v*)&xb[i] = cvt8(&x[i]);
        return;
    }
    const float* W; short* Wt; int N, obase, nx; float scale;
    if (id < 1024)      { W = Wq; Wt = Wqkvt; N = 2048; obase = 0;    nx = 32; scale = 1.0f; }
    else if (id < 1280) { W = Wk; Wt = Wqkvt; N = 512;  obase = 2048; nx = 8;  scale = 0.18033688011112042f; id -= 1024; }
    else if (id < 1536) { W = Wv; Wt = Wqkvt; N = 512;  obase = 2560; nx = 8;  scale = 1.0f; id -= 1280; }
    else                { W = Wo; Wt = Wot;   N = 2048; obase = 0;    nx = 32; scale = 1.0f; id -= 1536; }
    const int kt = (id / nx) * 64, n0 = (id % nx) * 64;
    const int t = threadIdx.x;
    const int r = t >> 4, c4 = (t & 15) * 4;
#pragma unroll
    for (int i = 0; i < 4; i++) {
        int kr = r + i * 16;
        f4v v = *(const f4v*)&W[(long)(kt + kr) * N + n0 + c4];
#pragma unroll
        for (int j = 0; j < 4; j++) tile[(c4 + j) * 72 + kr] = f2bf(v[j] * scale);
    }
    __syncthreads();
    const int nr = t >> 3, kc = (t & 7) * 8;
#pragma unroll
    for (int i = 0; i < 2; i++) {
        int n = nr + i * 32;
        *(s8v*)&Wt[(long)(obase + n0 + n) * 2048 + kt + kc] = *(const s8v*)&tile[n * 72 + kc];
    }
}

// ================== 256x256 4-phase GEMM (T2+T3+T4+T5) ==================
// (round-8 PASS) plus optional fused RoPE epilogue (round-9 PASS).
template <bool CF32, bool ROPE>
__global__ __launch_bounds__(512, 2) void gemm_bt8(const short* __restrict__ A,
                                                   const short* __restrict__ Bt,
                                                   void* __restrict__ Cv,
                                                   int K, int lda, int ldb, int ldc) {
    __shared__ __align__(16) short Ab[2][16384];   // [buf][256*64]
    __shared__ __align__(16) short Bb[2][16384];

    const int tid = threadIdx.x;
    const int lane = tid & 63;
    const int wave = tid >> 6;
    const int quad = lane >> 4;
    const int l15 = lane & 15;

    const int nwg = gridDim.x * gridDim.y;
    int f = blockIdx.y * gridDim.x + blockIdx.x;
    if ((nwg & 7) == 0) f = (f & 7) * (nwg >> 3) + (f >> 3);
    const int m0 = (f / gridDim.x) * 256;
    const int n0 = (f % gridDim.x) * 256;

    const int wm = (wave >> 2) * 128;
    const int wn = (wave & 3) * 64;

    const int rsub = lane >> 3;
    const int sslot = (lane & 7) ^ rsub;
    const short* aS[2][2];
    const short* bS[2][2];
#pragma unroll
    for (int h = 0; h < 2; h++)
#pragma unroll
        for (int i = 0; i < 2; i++) {
            int row = h * 128 + wave * 16 + i * 8 + rsub;
            aS[h][i] = A  + (long)(m0 + row) * lda + sslot * 8;
            bS[h][i] = Bt + (long)(n0 + row) * ldb + sslot * 8;
        }

    auto stageA = [&](int buf, int h, int kt) {
        char* d = (char*)&Ab[buf][0] + h * 16384 + wave * 2048;
        __builtin_amdgcn_global_load_lds((gp1_t)(aS[h][0] + (long)kt * 64), (lp3_t)d, 16, 0, 0);
        __builtin_amdgcn_global_load_lds((gp1_t)(aS[h][1] + (long)kt * 64), (lp3_t)(d + 1024), 16, 0, 0);
    };
    auto stageB = [&](int buf, int h, int kt) {
        char* d = (char*)&Bb[buf][0] + h * 16384 + wave * 2048;
        __builtin_amdgcn_global_load_lds((gp1_t)(bS[h][0] + (long)kt * 64), (lp3_t)d, 16, 0, 0);
        __builtin_amdgcn_global_load_lds((gp1_t)(bS[h][1] + (long)kt * 64), (lp3_t)(d + 1024), 16, 0, 0);
    };

    const int ks0 = (quad ^ (l15 & 7)) * 8;
    const int ks1 = ks0 ^ 32;

    f4v acc[2][4][2][2];   // [qm][mi][qn][ni]
#pragma unroll
    for (int a = 0; a < 2; a++)
#pragma unroll
        for (int b = 0; b < 4; b++)
#pragma unroll
            for (int c = 0; c < 2; c++)
#pragma unroll
                for (int d = 0; d < 2; d++) acc[a][b][c][d] = (f4v){0.f, 0.f, 0.f, 0.f};

    const int NT = K >> 6;

    stageB(0, 0, 0); stageB(0, 1, 0); stageA(0, 0, 0); stageA(0, 1, 0);
    stageB(1, 0, 1); stageB(1, 1, 1); stageA(1, 0, 1);
    asm volatile("s_waitcnt vmcnt(6)" ::: "memory");
    __builtin_amdgcn_s_barrier();

    for (int t = 0; t < NT; ++t) {
        const short* Ac = &Ab[t & 1][0];
        const short* Bc = &Bb[t & 1][0];
        const int nb = (t + 1) & 1;
        s8v af[4][2], bf0[2][2], bf1[2][2];

        // ---- phase 1
#pragma unroll
        for (int mi = 0; mi < 4; mi++) {
            const int row = wm + mi * 16 + l15;
            af[mi][0] = *(const s8v*)&Ac[row * 64 + ks0];
            af[mi][1] = *(const s8v*)&Ac[row * 64 + ks1];
        }
#pragma unroll
        for (int ni = 0; ni < 2; ni++) {
            const int row = wn + ni * 16 + l15;
            bf0[ni][0] = *(const s8v*)&Bc[row * 64 + ks0];
            bf0[ni][1] = *(const s8v*)&Bc[row * 64 + ks1];
        }
        if (t + 1 < NT) stageA(nb, 1, t + 1);
        __builtin_amdgcn_s_setprio(1);
#pragma unroll
        for (int mi = 0; mi < 4; mi++)
#pragma unroll
            for (int ni = 0; ni < 2; ni++) {
                acc[0][mi][0][ni] = __builtin_amdgcn_mfma_f32_16x16x32_bf16(af[mi][0], bf0[ni][0], acc[0][mi][0][ni], 0, 0, 0);
                acc[0][mi][0][ni] = __builtin_amdgcn_mfma_f32_16x16x32_bf16(af[mi][1], bf0[ni][1], acc[0][mi][0][ni], 0, 0, 0);
            }
        __builtin_amdgcn_s_setprio(0);
        __builtin_amdgcn_s_barrier();

        // ---- phase 2
#pragma unroll
        for (int ni = 0; ni < 2; ni++) {
            const int row = wn + 32 + ni * 16 + l15;
            bf1[ni][0] = *(const s8v*)&Bc[row * 64 + ks0];
            bf1[ni][1] = *(const s8v*)&Bc[row * 64 + ks1];
        }
        __builtin_amdgcn_s_setprio(1);
#pragma unroll
        for (int mi = 0; mi < 4; mi++)
#pragma unroll
            for (int ni = 0; ni < 2; ni++) {
                acc[0][mi][1][ni] = __builtin_amdgcn_mfma_f32_16x16x32_bf16(af[mi][0], bf1[ni][0], acc[0][mi][1][ni], 0, 0, 0);
                acc[0][mi][1][ni] = __builtin_amdgcn_mfma_f32_16x16x32_bf16(af[mi][1], bf1[ni][1], acc[0][mi][1][ni], 0, 0, 0);
            }
        __builtin_amdgcn_s_setprio(0);
        __builtin_amdgcn_s_barrier();

        // ---- phase 3
#pragma unroll
        for (int mi = 0; mi < 4; mi++) {
            const int row = wm + 64 + mi * 16 + l15;
            af[mi][0] = *(const s8v*)&Ac[row * 64 + ks0];
            af[mi][1] = *(const s8v*)&Ac[row * 64 + ks1];
        }
        if (t + 2 < NT) stageB(t & 1, 0, t + 2);
        __builtin_amdgcn_s_setprio(1);
#pragma unroll
        for (int mi = 0; mi < 4; mi++)
#pragma unroll
            for (int ni = 0; ni < 2; ni++) {
                acc[1][mi][0][ni] = __builtin_amdgcn_mfma_f32_16x16x32_bf16(af[mi][0], bf0[ni][0], acc[1][mi][0][ni], 0, 0, 0);
                acc[1][mi][0][ni] = __builtin_amdgcn_mfma_f32_16x16x32_bf16(af[mi][1], bf0[ni][1], acc[1][mi][0][ni], 0, 0, 0);
            }
        __builtin_amdgcn_s_setprio(0);
        __builtin_amdgcn_s_barrier();

        // ---- phase 4
        if (t + 2 < NT) { stageB(t & 1, 1, t + 2); stageA(t & 1, 0, t + 2); }
        __builtin_amdgcn_s_setprio(1);
#pragma unroll
        for (int mi = 0; mi < 4; mi++)
#pragma unroll
            for (int ni = 0; ni < 2; ni++) {
                acc[1][mi][1][ni] = __builtin_amdgcn_mfma_f32_16x16x32_bf16(af[mi][0], bf1[ni][0], acc[1][mi][1][ni], 0, 0, 0);
                acc[1][mi][1][ni] = __builtin_amdgcn_mfma_f32_16x16x32_bf16(af[mi][1], bf1[ni][1], acc[1][mi][1][ni], 0, 0, 0);
            }
        __builtin_amdgcn_s_setprio(0);
        if (t + 1 < NT) {
            if (t + 1 == NT - 1) asm volatile("s_waitcnt vmcnt(0)" ::: "memory");
            else                 asm volatile("s_waitcnt vmcnt(6)" ::: "memory");
            __builtin_amdgcn_s_barrier();
        }
    }

    // Fused RoPE (fp32, lane-local pairs), only for q/k heads (cols < 2560)
    if (ROPE && (n0 + wn) < 2560) {
        const float NLOG = -0.4152410118609203f;   // -log2(10000)/32
        const float fr0 = exp2f((float)l15 * NLOG);
        const float fr1 = exp2f((float)(16 + l15) * NLOG);
#pragma unroll
        for (int qm = 0; qm < 2; qm++)
#pragma unroll
            for (int mi = 0; mi < 4; mi++)
#pragma unroll
                for (int r = 0; r < 4; r++) {
                    const float s = (float)((m0 + wm + qm * 64 + mi * 16 + quad * 4 + r) & 2047);
#pragma unroll
                    for (int ni = 0; ni < 2; ni++) {
                        float sn, cs;
                        __sincosf(s * (ni ? fr1 : fr0), &sn, &cs);
                        float x1 = acc[qm][mi][0][ni][r];
                        float x2 = acc[qm][mi][1][ni][r];
                        acc[qm][mi][0][ni][r] = x1 * cs - x2 * sn;
                        acc[qm][mi][1][ni][r] = x2 * cs + x1 * sn;
                    }
                }
    }

#pragma unroll
    for (int qm = 0; qm < 2; qm++)
#pragma unroll
        for (int mi = 0; mi < 4; mi++)
#pragma unroll
            for (int qn = 0; qn < 2; qn++)
#pragma unroll
                for (int ni = 0; ni < 2; ni++)
#pragma unroll
                    for (int r = 0; r < 4; r++) {
                        int row = m0 + wm + qm * 64 + mi * 16 + quad * 4 + r;
                        int col = n0 + wn + qn * 32 + ni * 16 + l15;
                        float v = acc[qm][mi][qn][ni][r];
                        if (CF32) ((float*)Cv)[(long)row * ldc + col] = v;
                        else      ((short*)Cv)[(long)row * ldc + col] = f2bf(v);
                    }
}

// ================== 128x256 4-phase GEMM (full-chip variant, round-9 PASS) ==================
template <bool CF32>
__global__ __launch_bounds__(512, 2) void gemm_bt2(const short* __restrict__ A,
                                                   const short* __restrict__ Bt,
                                                   void* __restrict__ Cv,
                                                   int K, int lda, int ldb, int ldc) {
    __shared__ __align__(16) short Ab[2][8192];    // [buf][128*64]
    __shared__ __align__(16) short Bb[2][16384];   // [buf][256*64]

    const int tid = threadIdx.x;
    const int lane = tid & 63;
    const int wave = tid >> 6;
    const int quad = lane >> 4;
    const int l15 = lane & 15;

    const int nwg = gridDim.x * gridDim.y;
    int f = blockIdx.y * gridDim.x + blockIdx.x;
    if ((nwg & 7) == 0) f = (f & 7) * (nwg >> 3) + (f >> 3);
    const int m0 = (f / gridDim.x) * 128;
    const int n0 = (f % gridDim.x) * 256;

    const int wm = (wave >> 2) * 64;    // 0 or 64
    const int wn = (wave & 3) * 64;     // 0..192

    const int rsub = lane >> 3;
    const int sslot = (lane & 7) ^ rsub;
    const short* aS[2];
    const short* bS[4];
#pragma unroll
    for (int i = 0; i < 2; i++)
        aS[i] = A + (long)(m0 + wave * 16 + i * 8 + rsub) * lda + sslot * 8;
#pragma unroll
    for (int i = 0; i < 4; i++)
        bS[i] = Bt + (long)(n0 + wave * 32 + i * 8 + rsub) * ldb + sslot * 8;

    auto stageA = [&](int buf, int kt) {
        char* d = (char*)&Ab[buf][0] + wave * 2048;
        __builtin_amdgcn_global_load_lds((gp1_t)(aS[0] + (long)kt * 64), (lp3_t)d, 16, 0, 0);
        __builtin_amdgcn_global_load_lds((gp1_t)(aS[1] + (long)kt * 64), (lp3_t)(d + 1024), 16, 0, 0);
    };
    auto stageBh = [&](int buf, int h, int kt) {
        char* d = (char*)&Bb[buf][0] + wave * 4096 + h * 2048;
        __builtin_amdgcn_global_load_lds((gp1_t)(bS[2 * h] + (long)kt * 64), (lp3_t)d, 16, 0, 0);
        __builtin_amdgcn_global_load_lds((gp1_t)(bS[2 * h + 1] + (long)kt * 64), (lp3_t)(d + 1024), 16, 0, 0);
    };

    const int ks0 = (quad ^ (l15 & 7)) * 8;
    const int ks1 = ks0 ^ 32;

    f4v acc[4][2][2];   // [mi][qn][ni]
#pragma unroll
    for (int a = 0; a < 4; a++)
#pragma unroll
        for (int b = 0; b < 2; b++)
#pragma unroll
            for (int c = 0; c < 2; c++) acc[a][b][c] = (f4v){0.f, 0.f, 0.f, 0.f};

    const int NT = K >> 6;

    stageA(0, 0); stageBh(0, 0, 0); stageBh(0, 1, 0);
    stageA(1, 1); stageBh(1, 0, 1); stageBh(1, 1, 1);
    asm volatile("s_waitcnt vmcnt(6)" ::: "memory");
    __builtin_amdgcn_s_barrier();

    for (int t = 0; t < NT; ++t) {
        const short* Ac = &Ab[t & 1][0];
        const short* Bc = &Bb[t & 1][0];
        s8v af01[2][2], af23[2][2], bf0[2][2], bf1[2][2];

        // ---- phase 1
#pragma unroll
        for (int mi = 0; mi < 2; mi++) {
            const int row = wm + mi * 16 + l15;
            af01[mi][0] = *(const s8v*)&Ac[row * 64 + ks0];
            af01[mi][1] = *(const s8v*)&Ac[row * 64 + ks1];
        }
#pragma unroll
        for (int ni = 0; ni < 2; ni++) {
            const int row = wn + ni * 16 + l15;
            bf0[ni][0] = *(const s8v*)&Bc[row * 64 + ks0];
            bf0[ni][1] = *(const s8v*)&Bc[row * 64 + ks1];
        }
        __builtin_amdgcn_s_setprio(1);
#pragma unroll
        for (int mi = 0; mi < 2; mi++)
#pragma unroll
            for (int ni = 0; ni < 2; ni++) {
                acc[mi][0][ni] = __builtin_amdgcn_mfma_f32_16x16x32_bf16(af01[mi][0], bf0[ni][0], acc[mi][0][ni], 0, 0, 0);
                acc[mi][0][ni] = __builtin_amdgcn_mfma_f32_16x16x32_bf16(af01[mi][1], bf0[ni][1], acc[mi][0][ni], 0, 0, 0);
            }
        __builtin_amdgcn_s_setprio(0);
        __builtin_amdgcn_s_barrier();

        // ---- phase 2
#pragma unroll
        for (int ni = 0; ni < 2; ni++) {
            const int row = wn + 32 + ni * 16 + l15;
            bf1[ni][0] = *(const s8v*)&Bc[row * 64 + ks0];
            bf1[ni][1] = *(const s8v*)&Bc[row * 64 + ks1];
        }
        if (t + 2 < NT) stageBh(t & 1, 0, t + 2);
        __builtin_amdgcn_s_setprio(1);
#pragma unroll
        for (int mi = 0; mi < 2; mi++)
#pragma unroll
            for (int ni = 0; ni < 2; ni++) {
                acc[mi][1][ni] = __builtin_amdgcn_mfma_f32_16x16x32_bf16(af01[mi][0], bf1[ni][0], acc[mi][1][ni], 0, 0, 0);
                acc[mi][1][ni] = __builtin_amdgcn_mfma_f32_16x16x32_bf16(af01[mi][1], bf1[ni][1], acc[mi][1][ni], 0, 0, 0);
            }
        __builtin_amdgcn_s_setprio(0);
        __builtin_amdgcn_s_barrier();

        // ---- phase 3
#pragma unroll
        for (int mi = 0; mi < 2; mi++) {
            const int row = wm + 32 + mi * 16 + l15;
            af23[mi][0] = *(const s8v*)&Ac[row * 64 + ks0];
            af23[mi][1] = *(const s8v*)&Ac[row * 64 + ks1];
        }
        if (t + 2 < NT) stageBh(t & 1, 1, t + 2);
        __builtin_amdgcn_s_setprio(1);
#pragma unroll
        for (int mi = 0; mi < 2; mi++)
#pragma unroll
            for (int ni = 0; ni < 2; ni++) {
                acc[2 + mi][0][ni] = __builtin_amdgcn_mfma_f32_16x16x32_bf16(af23[mi][0], bf0[ni][0], acc[2 + mi][0][ni], 0, 0, 0);
                acc[2 + mi][0][ni] = __builtin_amdgcn_mfma_f32_16x16x32_bf16(af23[mi][1], bf0[ni][1], acc[2 + mi][0][ni], 0, 0, 0);
            }
        __builtin_amdgcn_s_setprio(0);
        __builtin_amdgcn_s_barrier();

        // ---- phase 4
        if (t + 2 < NT) stageA(t & 1, t + 2);
        __builtin_amdgcn_s_setprio(1);
#pragma unroll
        for (int mi = 0; mi < 2; mi++)
#pragma unroll
            for (int ni = 0; ni < 2; ni++) {
                acc[2 + mi][1][ni] = __builtin_amdgcn_mfma_f32_16x16x32_bf16(af23[mi][0], bf1[ni][0], acc[2 + mi][1][ni], 0, 0, 0);
                acc[2 + mi][1][ni] = __builtin_amdgcn_mfma_f32_16x16x32_bf16(af23[mi][1], bf1[ni][1], acc[2 + mi][1][ni], 0, 0, 0);
            }
        __builtin_amdgcn_s_setprio(0);
        if (t + 1 < NT) {
            if (t + 1 == NT - 1) asm volatile("s_waitcnt vmcnt(0)" ::: "memory");
            else                 asm volatile("s_waitcnt vmcnt(6)" ::: "memory");
            __builtin_amdgcn_s_barrier();
        }
    }

#pragma unroll
    for (int mi = 0; mi < 4; mi++)
#pragma unroll
        for (int qn = 0; qn < 2; qn++)
#pragma unroll
            for (int ni = 0; ni < 2; ni++)
#pragma unroll
                for (int r = 0; r < 4; r++) {
                    int row = m0 + wm + mi * 16 + quad * 4 + r;
                    int col = n0 + wn + qn * 32 + ni * 16 + l15;
                    float v = acc[mi][qn][ni][r];
                    if (CF32) ((float*)Cv)[(long)row * ldc + col] = v;
                    else      ((short*)Cv)[(long)row * ldc + col] = f2bf(v);
                }
}

// RoPE in-place on qkv cols [0,2560)  (fallback path only)
__global__ __launch_bounds__(256) void rope_kernel(short* __restrict__ qkv) {
    int tid = blockIdx.x * 256 + threadIdx.x;
    int p = tid % 1280;
    int row = tid / 1280;
    int head = p >> 5;
    int j = p & 31;
    int s = row & 2047;
    int c1 = head * 64 + j;
    float freq = exp2f(-(float)j * 0.4152410118609203f); // log2(10000)/32
    float ang = (float)s * freq;
    float sn, cs;
    __sincosf(ang, &sn, &cs);
    long base = (long)row * 3072;
    float x1 = bf2f(qkv[base + c1]);
    float x2 = bf2f(qkv[base + c1 + 32]);
    qkv[base + c1]      = f2bf(x1 * cs - x2 * sn);
    qkv[base + c1 + 32] = f2bf(x2 * cs + x1 * sn);
}

// V transpose with key-permutation pi applied per 64-key tile (round-10 PASS)
__global__ __launch_bounds__(256) void vtrans(const short* __restrict__ qkv,
                                              short* __restrict__ Vt_g) {
    __shared__ __align__(16) short tile[64 * 72];
    const int kt = blockIdx.x * 64;
    const int kvh = blockIdx.y;
    const int b = blockIdx.z;
    const int t = threadIdx.x;
#pragma unroll
    for (int cc = 0; cc < 2; cc++) {
        int ch = t + cc * 256;
        int key = ch >> 3, d0 = (ch & 7) * 8;
        s8v v = *(const s8v*)&qkv[(long)(b * 2048 + kt + key) * 3072 + 2560 + kvh * 64 + d0];
#pragma unroll
        for (int i = 0; i < 8; i++) tile[(d0 + i) * 72 + key] = v[i];
    }
    __syncthreads();
#pragma unroll
    for (int cc = 0; cc < 2; cc++) {
        int ch = t + cc * 256;
        int d = ch >> 3, c = ch & 7;
        int base1 = 32 * (c >> 2) + 4 * (c & 3);
        s4v lo = *(const s4v*)&tile[d * 72 + base1];
        s4v hi = *(const s4v*)&tile[d * 72 + base1 + 16];
        s8v w;
        w[0] = lo[0]; w[1] = lo[1]; w[2] = lo[2]; w[3] = lo[3];
        w[4] = hi[0]; w[5] = hi[1]; w[6] = hi[2]; w[7] = hi[3];
        *(s8v*)&Vt_g[(long)((b * 8 + kvh) * 64 + d) * 2048 + kt + c * 8] = w;
    }
}

// Flash attention v6: round-10 attn5 base (PASS) with rs computed via
// MFMA against a ones-fragment (matrix pipe) instead of VALU pk-adds;
// per-lane ors[r] is directly the denominator for its own output row
// (no shuffles, no LDS broadcast, no final barrier). LDS exactly 32 KB.
__global__ __launch_bounds__(256, 5) void attn6(short* __restrict__ qkv,
                                                const short* __restrict__ Vt_g) {
    __shared__ __align__(16) short KV[2][2][4096];   // [buf][K/V][64*64]

    const int tid = threadIdx.x;
    const int lane = tid & 63;
    const int wave = tid >> 6;
    const int quad = lane >> 4;
    const int l15 = lane & 15;

    int f = (blockIdx.z * 32 + blockIdx.y) * 16 + blockIdx.x;
    f = (f & 7) * 128 + (f >> 3);
    const int b = f >> 9;
    const int h = (f >> 4) & 31;
    const int kvh = h >> 2;
    const int q0 = (f & 15) * 128;

    const long kbase = ((long)b * 2048) * 3072 + 2048 + kvh * 64;
    const long vtbase = (long)(b * 8 + kvh) * 64 * 2048;

    const long qrow = (long)b * 2048 + q0 + wave * 32 + l15;
    const short* qp = qkv + qrow * 3072 + h * 64 + quad * 8;
    const s8v qf00 = *(const s8v*)(qp);
    const s8v qf01 = *(const s8v*)(qp + 32);
    const s8v qf10 = *(const s8v*)(qp + 16 * 3072);
    const s8v qf11 = *(const s8v*)(qp + 16 * 3072 + 32);

    const int rA = wave * 8 + (lane >> 3);
    const int sslot = (lane & 7) ^ (lane >> 3);
    const short* kA = qkv + kbase + (long)rA * 3072 + sslot * 8;
    const short* kB = kA + (long)32 * 3072;
    const short* vA = Vt_g + vtbase + (long)rA * 2048 + sslot * 8;
    const short* vB = vA + (long)32 * 2048;

    {
        char* kd = (char*)&KV[0][0][0] + wave * 1024;
        char* vd = (char*)&KV[0][1][0] + wave * 1024;
        __builtin_amdgcn_global_load_lds((gp1_t)kA, (lp3_t)kd, 16, 0, 0);
        __builtin_amdgcn_global_load_lds((gp1_t)kB, (lp3_t)(kd + 4096), 16, 0, 0);
        __builtin_amdgcn_global_load_lds((gp1_t)vA, (lp3_t)vd, 16, 0, 0);
        __builtin_amdgcn_global_load_lds((gp1_t)vB, (lp3_t)(vd + 4096), 16, 0, 0);
    }
    __syncthreads();

    const int ks0 = ((quad ^ (l15 & 7)) << 3);
    const int ks1 = ks0 ^ 32;

    const s8v vones = (s8v){16256, 16256, 16256, 16256, 16256, 16256, 16256, 16256}; // bf16 1.0

    f4v o0[4], o1[4];
    f4v ors0 = (f4v){0.f, 0.f, 0.f, 0.f};
    f4v ors1 = (f4v){0.f, 0.f, 0.f, 0.f};
#pragma unroll
    for (int ni = 0; ni < 4; ni++) { o0[ni] = (f4v){0.f, 0.f, 0.f, 0.f}; o1[ni] = (f4v){0.f, 0.f, 0.f, 0.f}; }

    for (int t = 0; t < 32; ++t) {
        const short* Kb = &KV[t & 1][0][0];
        const short* Vb = &KV[t & 1][1][0];

        if (t < 31) {
            const long ko = (long)(t + 1) * (64 * 3072);
            const long vo = (long)(t + 1) * 64;
            char* kd = (char*)&KV[(t + 1) & 1][0][0] + wave * 1024;
            char* vd = (char*)&KV[(t + 1) & 1][1][0] + wave * 1024;
            __builtin_amdgcn_global_load_lds((gp1_t)(kA + ko), (lp3_t)kd, 16, 0, 0);
            __builtin_amdgcn_global_load_lds((gp1_t)(kB + ko), (lp3_t)(kd + 4096), 16, 0, 0);
            __builtin_amdgcn_global_load_lds((gp1_t)(vA + vo), (lp3_t)vd, 16, 0, 0);
            __builtin_amdgcn_global_load_lds((gp1_t)(vB + vo), (lp3_t)(vd + 4096), 16, 0, 0);
        }

        // QK^T swapped: lane (quad,l15) reg r holds score-24 for
        // key = ni*16+quad*4+r, q = l15
        unsigned pk0[4][2], pk1[4][2];
#pragma unroll
        for (int ni = 0; ni < 4; ni++) {
            const int ro = (ni * 16 + l15) * 64;
            const s8v kf0 = *(const s8v*)&Kb[ro + ks0];
            const s8v kf1 = *(const s8v*)&Kb[ro + ks1];
            f4v a = (f4v){-24.f, -24.f, -24.f, -24.f};
            a = __builtin_amdgcn_mfma_f32_16x16x32_bf16(kf0, qf00, a, 0, 0, 0);
            a = __builtin_amdgcn_mfma_f32_16x16x32_bf16(kf1, qf01, a, 0, 0, 0);
            {
                pk0[ni][0] = cvt_pk_bf16(exp2f(a[0]), exp2f(a[1]));
                pk0[ni][1] = cvt_pk_bf16(exp2f(a[2]), exp2f(a[3]));
            }
            f4v c = (f4v){-24.f, -24.f, -24.f, -24.f};
            c = __builtin_amdgcn_mfma_f32_16x16x32_bf16(kf0, qf10, c, 0, 0, 0);
            c = __builtin_amdgcn_mfma_f32_16x16x32_bf16(kf1, qf11, c, 0, 0, 0);
            {
                pk1[ni][0] = cvt_pk_bf16(exp2f(c[0]), exp2f(c[1]));
                pk1[ni][1] = cvt_pk_bf16(exp2f(c[2]), exp2f(c[3]));
            }
        }

        // In-lane PV A-fragments (pi_v-permuted V)
        union PU { u4v u; s8v s; };
        PU pa0, pa1, pb0, pb1;
        pa0.u = (u4v){pk0[0][0], pk0[0][1], pk0[1][0], pk0[1][1]};
        pa1.u = (u4v){pk0[2][0], pk0[2][1], pk0[3][0], pk0[3][1]};
        pb0.u = (u4v){pk1[0][0], pk1[0][1], pk1[1][0], pk1[1][1]};
        pb1.u = (u4v){pk1[2][0], pk1[2][1], pk1[3][0], pk1[3][1]};

        // rs = P * ones on the matrix pipe
        ors0 = __builtin_amdgcn_mfma_f32_16x16x32_bf16(pa0.s, vones, ors0, 0, 0, 0);
        ors0 = __builtin_amdgcn_mfma_f32_16x16x32_bf16(pa1.s, vones, ors0, 0, 0, 0);
        ors1 = __builtin_amdgcn_mfma_f32_16x16x32_bf16(pb0.s, vones, ors1, 0, 0, 0);
        ors1 = __builtin_amdgcn_mfma_f32_16x16x32_bf16(pb1.s, vones, ors1, 0, 0, 0);

#pragma unroll
        for (int ni = 0; ni < 4; ni++) {
            const int ro = (ni * 16 + l15) * 64;
            const s8v vf0 = *(const s8v*)&Vb[ro + ks0];
            const s8v vf1 = *(const s8v*)&Vb[ro + ks1];
            o0[ni] = __builtin_amdgcn_mfma_f32_16x16x32_bf16(pa0.s, vf0, o0[ni], 0, 0, 0);
            o0[ni] = __builtin_amdgcn_mfma_f32_16x16x32_bf16(pa1.s, vf1, o0[ni], 0, 0, 0);
            o1[ni] = __builtin_amdgcn_mfma_f32_16x16x32_bf16(pb0.s, vf0, o1[ni], 0, 0, 0);
            o1[ni] = __builtin_amdgcn_mfma_f32_16x16x32_bf16(pb1.s, vf1, o1[ni], 0, 0, 0);
        }
        __syncthreads();
    }

#pragma unroll
    for (int r = 0; r < 4; r++) {
        const float i0 = 1.0f / ors0[r];
        const float i1 = 1.0f / ors1[r];
        const long ob0 = ((long)b * 2048 + q0 + wave * 32 + quad * 4 + r) * 3072 + h * 64;
        const long ob1 = ob0 + 16 * 3072;
#pragma unroll
        for (int ni = 0; ni < 4; ni++) {
            qkv[ob0 + ni * 16 + l15] = f2bf(o0[ni][r] * i0);
            qkv[ob1 + ni * 16 + l15] = f2bf(o1[ni][r] * i1);
        }
    }
}

// ======================= FALLBACK PATH (round-6, known-PASS) =======================

template <bool AF32, bool CF32>
__global__ __launch_bounds__(256) void gemm_bn(const void* __restrict__ Av,
                                               const float* __restrict__ B,
                                               void* __restrict__ Cv,
                                               int K, int N, int lda, int ldc) {
    __shared__ __align__(16) short As[128 * 40];
    __shared__ __align__(16) short Bs[128 * 40];
    const int tid = threadIdx.x;
    const int lane = tid & 63;
    const int wave = tid >> 6;
    const int quad = lane >> 4;
    const int l15 = lane & 15;
    const int m0 = blockIdx.y * 128;
    const int n0 = blockIdx.x * 128;
    const int wm = (wave & 1) * 64;
    const int wn = (wave >> 1) * 64;

    f4v acc[4][4];
#pragma unroll
    for (int i = 0; i < 4; i++)
#pragma unroll
        for (int j = 0; j < 4; j++) acc[i][j] = (f4v){0.f, 0.f, 0.f, 0.f};

    const int ar0 = tid >> 2, akc0 = (tid & 3) * 8;
    const int ar1 = (tid + 256) >> 2, akc1 = ((tid + 256) & 3) * 8;
    const int bk0 = tid >> 4, bnc0 = (tid & 15) * 8;
    const int bk1 = (tid + 256) >> 4, bnc1 = ((tid + 256) & 15) * 8;

    for (int k0 = 0; k0 < K; k0 += 32) {
        __syncthreads();
        if (AF32) {
            const float* A = (const float*)Av;
            *(s8v*)(&As[ar0 * 40 + akc0]) = cvt8(&A[(long)(m0 + ar0) * lda + k0 + akc0]);
            *(s8v*)(&As[ar1 * 40 + akc1]) = cvt8(&A[(long)(m0 + ar1) * lda + k0 + akc1]);
        } else {
            const short* A = (const short*)Av;
            *(s8v*)(&As[ar0 * 40 + akc0]) = *(const s8v*)(&A[(long)(m0 + ar0) * lda + k0 + akc0]);
            *(s8v*)(&As[ar1 * 40 + akc1]) = *(const s8v*)(&A[(long)(m0 + ar1) * lda + k0 + akc1]);
        }
        s8v b0 = cvt8(&B[(long)(k0 + bk0) * N + n0 + bnc0]);
        s8v b1 = cvt8(&B[(long)(k0 + bk1) * N + n0 + bnc1]);
#pragma unroll
        for (int i = 0; i < 8; i++) Bs[(bnc0 + i) * 40 + bk0] = b0[i];
#pragma unroll
        for (int i = 0; i < 8; i++) Bs[(bnc1 + i) * 40 + bk1] = b1[i];
        __syncthreads();
        s8v af[4], bfr[4];
#pragma unroll
        for (int mi = 0; mi < 4; mi++)
            af[mi] = *(const s8v*)(&As[(wm + mi * 16 + l15) * 40 + quad * 8]);
#pragma unroll
        for (int ni = 0; ni < 4; ni++)
            bfr[ni] = *(const s8v*)(&Bs[(wn + ni * 16 + l15) * 40 + quad * 8]);
#pragma unroll
        for (int mi = 0; mi < 4; mi++)
#pragma unroll
            for (int ni = 0; ni < 4; ni++)
                acc[mi][ni] = __builtin_amdgcn_mfma_f32_16x16x32_bf16(af[mi], bfr[ni], acc[mi][ni], 0, 0, 0);
    }
#pragma unroll
    for (int mi = 0; mi < 4; mi++)
#pragma unroll
        for (int ni = 0; ni < 4; ni++)
#pragma unroll
            for (int r = 0; r < 4; r++) {
                int row = m0 + wm + mi * 16 + quad * 4 + r;
                int col = n0 + wn + ni * 16 + l15;
                if (CF32) ((float*)Cv)[(long)row * ldc + col] = acc[mi][ni][r];
                else      ((short*)Cv)[(long)row * ldc + col] = f2bf(acc[mi][ni][r]);
            }
}

__global__ __launch_bounds__(256) void attn_kernel(short* __restrict__ qkv) {
    __shared__ __align__(16) short Qs[64 * 72];
    __shared__ __align__(16) short Ks[64 * 72];
    __shared__ __align__(16) short Vt[64 * 72];
    __shared__ __align__(16) short Ps[4][16 * 72];

    const int tid = threadIdx.x;
    const int lane = tid & 63;
    const int wave = tid >> 6;
    const int quad = lane >> 4;
    const int l15 = lane & 15;
    const int b = blockIdx.z;
    const int h = blockIdx.y;
    const int kvh = h >> 2;
    const int q0 = blockIdx.x * 64;

    const long qbase = ((long)b * 2048 + q0) * 3072 + h * 64;
    const long kbase = ((long)b * 2048) * 3072 + 2048 + kvh * 64;
    const long vbase = kbase + 512;

#pragma unroll
    for (int cc = 0; cc < 2; cc++) {
        int ch = tid + cc * 256;
        int r = ch >> 3, d0 = (ch & 7) * 8;
        *(s8v*)(&Qs[r * 72 + d0]) = *(const s8v*)(&qkv[qbase + (long)r * 3072 + d0]);
    }
    __syncthreads();
    s8v qf[2];
    qf[0] = *(const s8v*)(&Qs[(wave * 16 + l15) * 72 + quad * 8]);
    qf[1] = *(const s8v*)(&Qs[(wave * 16 + l15) * 72 + 32 + quad * 8]);

    float m_i[4], l_i[4];
    f4v o[4];
#pragma unroll
    for (int r = 0; r < 4; r++) { m_i[r] = -1e30f; l_i[r] = 0.0f; }
#pragma unroll
    for (int ni = 0; ni < 4; ni++) o[ni] = (f4v){0.f, 0.f, 0.f, 0.f};

    for (int kt = 0; kt < 2048; kt += 64) {
        __syncthreads();
#pragma unroll
        for (int cc = 0; cc < 2; cc++) {
            int ch = tid + cc * 256;
            int r = ch >> 3, d0 = (ch & 7) * 8;
            *(s8v*)(&Ks[r * 72 + d0]) = *(const s8v*)(&qkv[kbase + (long)(kt + r) * 3072 + d0]);
            s8v v = *(const s8v*)(&qkv[vbase + (long)(kt + r) * 3072 + d0]);
            int g = d0 >> 3;
            int chn = ((r >> 3) ^ g) * 8 + (r & 7);
#pragma unroll
            for (int i = 0; i < 8; i++) Vt[(d0 + i) * 72 + chn] = v[i];
        }
        __syncthreads();

        f4v sc[4];
#pragma unroll
        for (int ni = 0; ni < 4; ni++) {
            s8v kf0 = *(const s8v*)(&Ks[(ni * 16 + l15) * 72 + quad * 8]);
            s8v kf1 = *(const s8v*)(&Ks[(ni * 16 + l15) * 72 + 32 + quad * 8]);
            f4v a = (f4v){0.f, 0.f, 0.f, 0.f};
            a = __builtin_amdgcn_mfma_f32_16x16x32_bf16(qf[0], kf0, a, 0, 0, 0);
            a = __builtin_amdgcn_mfma_f32_16x16x32_bf16(qf[1], kf1, a, 0, 0, 0);
            sc[ni] = a * 0.125f;
        }
        float alpha[4], rs[4];
#pragma unroll
        for (int r = 0; r < 4; r++) {
            float v = fmaxf(fmaxf(sc[0][r], sc[1][r]), fmaxf(sc[2][r], sc[3][r]));
            v = fmaxf(v, __shfl_xor(v, 1));
            v = fmaxf(v, __shfl_xor(v, 2));
            v = fmaxf(v, __shfl_xor(v, 4));
            v = fmaxf(v, __shfl_xor(v, 8));
            float mn = fmaxf(m_i[r], v);
            alpha[r] = __expf(m_i[r] - mn);
            m_i[r] = mn;
            rs[r] = 0.f;
        }
#pragma unroll
        for (int ni = 0; ni < 4; ni++)
#pragma unroll
            for (int r = 0; r < 4; r++) {
                float pv = __expf(sc[ni][r] - m_i[r]);
                sc[ni][r] = pv;
                rs[r] += pv;
            }
#pragma unroll
        for (int r = 0; r < 4; r++) {
            float v = rs[r];
            v += __shfl_xor(v, 1);
            v += __shfl_xor(v, 2);
            v += __shfl_xor(v, 4);
            v += __shfl_xor(v, 8);
            l_i[r] = l_i[r] * alpha[r] + v;
        }
#pragma unroll
        for (int ni = 0; ni < 4; ni++)
#pragma unroll
            for (int r = 0; r < 4; r++) {
                int row = quad * 4 + r;
                int key = ni * 16 + l15;
                int chn = ((key >> 3) ^ (row >> 3)) * 8 + (key & 7);
                Ps[wave][row * 72 + chn] = f2bf(sc[ni][r]);
            }
        __syncthreads();
#pragma unroll
        for (int ni = 0; ni < 4; ni++) {
            f4v t = o[ni];
            t[0] *= alpha[0]; t[1] *= alpha[1]; t[2] *= alpha[2]; t[3] *= alpha[3];
            o[ni] = t;
        }
        s8v pf0 = *(const s8v*)(&Ps[wave][l15 * 72 + ((quad ^ (l15 >> 3)) * 8)]);
        s8v pf1 = *(const s8v*)(&Ps[wave][l15 * 72 + (((4 + quad) ^ (l15 >> 3)) * 8)]);
#pragma unroll
        for (int ni = 0; ni < 4; ni++) {
            int d = ni * 16 + l15;
            s8v vf0 = *(const s8v*)(&Vt[d * 72 + ((quad ^ (d >> 3)) * 8)]);
            s8v vf1 = *(const s8v*)(&Vt[d * 72 + (((4 + quad) ^ (d >> 3)) * 8)]);
            o[ni] = __builtin_amdgcn_mfma_f32_16x16x32_bf16(pf0, vf0, o[ni], 0, 0, 0);
            o[ni] = __builtin_amdgcn_mfma_f32_16x16x32_bf16(pf1, vf1, o[ni], 0, 0, 0);
        }
    }
#pragma unroll
    for (int r = 0; r < 4; r++) {
        float inv = 1.0f / l_i[r];
        int srow = q0 + wave * 16 + quad * 4 + r;
        long obase = ((long)b * 2048 + srow) * 3072 + h * 64;
#pragma unroll
        for (int ni = 0; ni < 4; ni++)
            qkv[obase + ni * 16 + l15] = f2bf(o[ni][r] * inv);
    }
}

extern "C" void kernel_launch(void* const* d_in, const int* in_sizes, int n_in,
                              void* d_out, int out_size, void* d_ws, size_t ws_size,
                              hipStream_t stream) {
    (void)in_sizes; (void)n_in; (void)out_size;
    const float* x  = (const float*)d_in[0];
    const float* Wq = (const float*)d_in[1];
    const float* Wk = (const float*)d_in[2];
    const float* Wv = (const float*)d_in[3];
    const float* Wo = (const float*)d_in[4];

    const size_t need = 67108864ULL; // 64 MiB
    if (ws_size >= need) {
        short* xb    = (short*)d_ws;              // 4096x2048
        short* Wqkvt = xb + 8388608;              // 3072x2048
        short* Wot   = Wqkvt + 6291456;           // 2048x2048
        short* qkv   = Wot + 4194304;             // 4096x3072
        short* Vt_g  = qkv + 12582912;            // 16x64x2048

        prep<<<6656, 256, 0, stream>>>(x, Wq, Wk, Wv, Wo, xb, Wqkvt, Wot);
        gemm_bt8<false, true><<<dim3(12, 16), 512, 0, stream>>>(xb, Wqkvt, qkv, 2048, 2048, 2048, 3072);
        vtrans<<<dim3(32, 8, 2), 256, 0, stream>>>(qkv, Vt_g);
        attn6<<<dim3(16, 32, 2), 256, 0, stream>>>(qkv, Vt_g);
        gemm_bt2<true><<<dim3(8, 32), 512, 0, stream>>>(qkv, Wot, d_out, 2048, 3072, 2048, 2048);
    } else {
        short* qkv = (short*)d_ws;
        gemm_bn<true, false><<<dim3(16, 32), 256, 0, stream>>>(x, Wq, qkv,        2048, 2048, 2048, 3072);
        gemm_bn<true, false><<<dim3(4, 32), 256, 0, stream>>>(x, Wk, qkv + 2048, 2048,  512, 2048, 3072);
        gemm_bn<true, false><<<dim3(4, 32), 256, 0, stream>>>(x, Wv, qkv + 2560, 2048,  512, 2048, 3072);
        rope_kernel<<<dim3(20480), 256, 0, stream>>>(qkv);
        attn_kernel<<<dim3(32, 32, 2), 256, 0, stream>>>(qkv);
        gemm_bn<false, true><<<dim3(16, 32), 256, 0, stream>>>(qkv, Wo, d_out, 2048, 2048, 3072, 2048);
    }
}

// Round 12
// 307.438 us; speedup vs baseline: 1.0841x; 1.0841x over previous
//
#include <hip/hip_runtime.h>

typedef short s8v __attribute__((ext_vector_type(8)));
typedef short s4v __attribute__((ext_vector_type(4)));
typedef unsigned u4v __attribute__((ext_vector_type(4)));
typedef float f2v __attribute__((ext_vector_type(2)));
typedef float f4v __attribute__((ext_vector_type(4)));

typedef const __attribute__((address_space(1))) char* gp1_t;
typedef __attribute__((address_space(3))) char* lp3_t;

__device__ __forceinline__ float bf2f(short s) {
    union { unsigned u; float f; } c;
    c.u = ((unsigned)(unsigned short)s) << 16;
    return c.f;
}
__device__ __forceinline__ short f2bf(float f) {
    union { float f; unsigned u; } c; c.f = f;
    unsigned r = (c.u + 0x7FFFu + ((c.u >> 16) & 1u)) >> 16;
    return (short)r;
}
__device__ __forceinline__ unsigned cvt_pk_bf16(float a, float b) {
    unsigned r;
    asm("v_cvt_pk_bf16_f32 %0, %1, %2" : "=v"(r) : "v"(a), "v"(b));
    return r;
}
__device__ __forceinline__ s8v cvt8(const float* __restrict__ p) {
    f4v a = *(const f4v*)p;
    f4v b = *(const f4v*)(p + 4);
    s8v r;
    r[0] = f2bf(a[0]); r[1] = f2bf(a[1]); r[2] = f2bf(a[2]); r[3] = f2bf(a[3]);
    r[4] = f2bf(b[0]); r[5] = f2bf(b[1]); r[6] = f2bf(b[2]); r[7] = f2bf(b[3]);
    return r;
}

// ======================= FAST PATH (ws >= 64 MiB) =======================

// Merged preprocessing (round-11 PASS): blocks [0,2560) W transposes,
// blocks [2560,6656) x fp32->bf16 copy.
__global__ __launch_bounds__(256) void prep(const float* __restrict__ x,
                                            const float* __restrict__ Wq,
                                            const float* __restrict__ Wk,
                                            const float* __restrict__ Wv,
                                            const float* __restrict__ Wo,
                                            short* __restrict__ xb,
                                            short* __restrict__ Wqkvt,
                                            short* __restrict__ Wot) {
    __shared__ __align__(16) short tile[64 * 72];
    int id = blockIdx.x;
    if (id >= 2560) {
        long i = ((long)(id - 2560) * 256 + threadIdx.x) * 8;
        *(s8v*)&xb[i] = cvt8(&x[i]);
        return;
    }
    const float* W; short* Wt; int N, obase, nx; float scale;
    if (id < 1024)      { W = Wq; Wt = Wqkvt; N = 2048; obase = 0;    nx = 32; scale = 1.0f; }
    else if (id < 1280) { W = Wk; Wt = Wqkvt; N = 512;  obase = 2048; nx = 8;  scale = 0.18033688011112042f; id -= 1024; }
    else if (id < 1536) { W = Wv; Wt = Wqkvt; N = 512;  obase = 2560; nx = 8;  scale = 1.0f; id -= 1280; }
    else                { W = Wo; Wt = Wot;   N = 2048; obase = 0;    nx = 32; scale = 1.0f; id -= 1536; }
    const int kt = (id / nx) * 64, n0 = (id % nx) * 64;
    const int t = threadIdx.x;
    const int r = t >> 4, c4 = (t & 15) * 4;
#pragma unroll
    for (int i = 0; i < 4; i++) {
        int kr = r + i * 16;
        f4v v = *(const f4v*)&W[(long)(kt + kr) * N + n0 + c4];
#pragma unroll
        for (int j = 0; j < 4; j++) tile[(c4 + j) * 72 + kr] = f2bf(v[j] * scale);
    }
    __syncthreads();
    const int nr = t >> 3, kc = (t & 7) * 8;
#pragma unroll
    for (int i = 0; i < 2; i++) {
        int n = nr + i * 32;
        *(s8v*)&Wt[(long)(obase + n0 + n) * 2048 + kt + kc] = *(const s8v*)&tile[n * 72 + kc];
    }
}

// ================== 256x256 4-phase GEMM (T2+T3+T4+T5) ==================
// (round-8 PASS) plus optional fused RoPE epilogue (round-9 PASS).
template <bool CF32, bool ROPE>
__global__ __launch_bounds__(512, 2) void gemm_bt8(const short* __restrict__ A,
                                                   const short* __restrict__ Bt,
                                                   void* __restrict__ Cv,
                                                   int K, int lda, int ldb, int ldc) {
    __shared__ __align__(16) short Ab[2][16384];   // [buf][256*64]
    __shared__ __align__(16) short Bb[2][16384];

    const int tid = threadIdx.x;
    const int lane = tid & 63;
    const int wave = tid >> 6;
    const int quad = lane >> 4;
    const int l15 = lane & 15;

    const int nwg = gridDim.x * gridDim.y;
    int f = blockIdx.y * gridDim.x + blockIdx.x;
    if ((nwg & 7) == 0) f = (f & 7) * (nwg >> 3) + (f >> 3);
    const int m0 = (f / gridDim.x) * 256;
    const int n0 = (f % gridDim.x) * 256;

    const int wm = (wave >> 2) * 128;
    const int wn = (wave & 3) * 64;

    const int rsub = lane >> 3;
    const int sslot = (lane & 7) ^ rsub;
    const short* aS[2][2];
    const short* bS[2][2];
#pragma unroll
    for (int h = 0; h < 2; h++)
#pragma unroll
        for (int i = 0; i < 2; i++) {
            int row = h * 128 + wave * 16 + i * 8 + rsub;
            aS[h][i] = A  + (long)(m0 + row) * lda + sslot * 8;
            bS[h][i] = Bt + (long)(n0 + row) * ldb + sslot * 8;
        }

    auto stageA = [&](int buf, int h, int kt) {
        char* d = (char*)&Ab[buf][0] + h * 16384 + wave * 2048;
        __builtin_amdgcn_global_load_lds((gp1_t)(aS[h][0] + (long)kt * 64), (lp3_t)d, 16, 0, 0);
        __builtin_amdgcn_global_load_lds((gp1_t)(aS[h][1] + (long)kt * 64), (lp3_t)(d + 1024), 16, 0, 0);
    };
    auto stageB = [&](int buf, int h, int kt) {
        char* d = (char*)&Bb[buf][0] + h * 16384 + wave * 2048;
        __builtin_amdgcn_global_load_lds((gp1_t)(bS[h][0] + (long)kt * 64), (lp3_t)d, 16, 0, 0);
        __builtin_amdgcn_global_load_lds((gp1_t)(bS[h][1] + (long)kt * 64), (lp3_t)(d + 1024), 16, 0, 0);
    };

    const int ks0 = (quad ^ (l15 & 7)) * 8;
    const int ks1 = ks0 ^ 32;

    f4v acc[2][4][2][2];   // [qm][mi][qn][ni]
#pragma unroll
    for (int a = 0; a < 2; a++)
#pragma unroll
        for (int b = 0; b < 4; b++)
#pragma unroll
            for (int c = 0; c < 2; c++)
#pragma unroll
                for (int d = 0; d < 2; d++) acc[a][b][c][d] = (f4v){0.f, 0.f, 0.f, 0.f};

    const int NT = K >> 6;

    stageB(0, 0, 0); stageB(0, 1, 0); stageA(0, 0, 0); stageA(0, 1, 0);
    stageB(1, 0, 1); stageB(1, 1, 1); stageA(1, 0, 1);
    asm volatile("s_waitcnt vmcnt(6)" ::: "memory");
    __builtin_amdgcn_s_barrier();

    for (int t = 0; t < NT; ++t) {
        const short* Ac = &Ab[t & 1][0];
        const short* Bc = &Bb[t & 1][0];
        const int nb = (t + 1) & 1;
        s8v af[4][2], bf0[2][2], bf1[2][2];

        // ---- phase 1
#pragma unroll
        for (int mi = 0; mi < 4; mi++) {
            const int row = wm + mi * 16 + l15;
            af[mi][0] = *(const s8v*)&Ac[row * 64 + ks0];
            af[mi][1] = *(const s8v*)&Ac[row * 64 + ks1];
        }
#pragma unroll
        for (int ni = 0; ni < 2; ni++) {
            const int row = wn + ni * 16 + l15;
            bf0[ni][0] = *(const s8v*)&Bc[row * 64 + ks0];
            bf0[ni][1] = *(const s8v*)&Bc[row * 64 + ks1];
        }
        if (t + 1 < NT) stageA(nb, 1, t + 1);
        __builtin_amdgcn_s_setprio(1);
#pragma unroll
        for (int mi = 0; mi < 4; mi++)
#pragma unroll
            for (int ni = 0; ni < 2; ni++) {
                acc[0][mi][0][ni] = __builtin_amdgcn_mfma_f32_16x16x32_bf16(af[mi][0], bf0[ni][0], acc[0][mi][0][ni], 0, 0, 0);
                acc[0][mi][0][ni] = __builtin_amdgcn_mfma_f32_16x16x32_bf16(af[mi][1], bf0[ni][1], acc[0][mi][0][ni], 0, 0, 0);
            }
        __builtin_amdgcn_s_setprio(0);
        __builtin_amdgcn_s_barrier();

        // ---- phase 2
#pragma unroll
        for (int ni = 0; ni < 2; ni++) {
            const int row = wn + 32 + ni * 16 + l15;
            bf1[ni][0] = *(const s8v*)&Bc[row * 64 + ks0];
            bf1[ni][1] = *(const s8v*)&Bc[row * 64 + ks1];
        }
        __builtin_amdgcn_s_setprio(1);
#pragma unroll
        for (int mi = 0; mi < 4; mi++)
#pragma unroll
            for (int ni = 0; ni < 2; ni++) {
                acc[0][mi][1][ni] = __builtin_amdgcn_mfma_f32_16x16x32_bf16(af[mi][0], bf1[ni][0], acc[0][mi][1][ni], 0, 0, 0);
                acc[0][mi][1][ni] = __builtin_amdgcn_mfma_f32_16x16x32_bf16(af[mi][1], bf1[ni][1], acc[0][mi][1][ni], 0, 0, 0);
            }
        __builtin_amdgcn_s_setprio(0);
        __builtin_amdgcn_s_barrier();

        // ---- phase 3
#pragma unroll
        for (int mi = 0; mi < 4; mi++) {
            const int row = wm + 64 + mi * 16 + l15;
            af[mi][0] = *(const s8v*)&Ac[row * 64 + ks0];
            af[mi][1] = *(const s8v*)&Ac[row * 64 + ks1];
        }
        if (t + 2 < NT) stageB(t & 1, 0, t + 2);
        __builtin_amdgcn_s_setprio(1);
#pragma unroll
        for (int mi = 0; mi < 4; mi++)
#pragma unroll
            for (int ni = 0; ni < 2; ni++) {
                acc[1][mi][0][ni] = __builtin_amdgcn_mfma_f32_16x16x32_bf16(af[mi][0], bf0[ni][0], acc[1][mi][0][ni], 0, 0, 0);
                acc[1][mi][0][ni] = __builtin_amdgcn_mfma_f32_16x16x32_bf16(af[mi][1], bf0[ni][1], acc[1][mi][0][ni], 0, 0, 0);
            }
        __builtin_amdgcn_s_setprio(0);
        __builtin_amdgcn_s_barrier();

        // ---- phase 4
        if (t + 2 < NT) { stageB(t & 1, 1, t + 2); stageA(t & 1, 0, t + 2); }
        __builtin_amdgcn_s_setprio(1);
#pragma unroll
        for (int mi = 0; mi < 4; mi++)
#pragma unroll
            for (int ni = 0; ni < 2; ni++) {
                acc[1][mi][1][ni] = __builtin_amdgcn_mfma_f32_16x16x32_bf16(af[mi][0], bf1[ni][0], acc[1][mi][1][ni], 0, 0, 0);
                acc[1][mi][1][ni] = __builtin_amdgcn_mfma_f32_16x16x32_bf16(af[mi][1], bf1[ni][1], acc[1][mi][1][ni], 0, 0, 0);
            }
        __builtin_amdgcn_s_setprio(0);
        if (t + 1 < NT) {
            if (t + 1 == NT - 1) asm volatile("s_waitcnt vmcnt(0)" ::: "memory");
            else                 asm volatile("s_waitcnt vmcnt(6)" ::: "memory");
            __builtin_amdgcn_s_barrier();
        }
    }

    // Fused RoPE (fp32, lane-local pairs), only for q/k heads (cols < 2560)
    if (ROPE && (n0 + wn) < 2560) {
        const float NLOG = -0.4152410118609203f;   // -log2(10000)/32
        const float fr0 = exp2f((float)l15 * NLOG);
        const float fr1 = exp2f((float)(16 + l15) * NLOG);
#pragma unroll
        for (int qm = 0; qm < 2; qm++)
#pragma unroll
            for (int mi = 0; mi < 4; mi++)
#pragma unroll
                for (int r = 0; r < 4; r++) {
                    const float s = (float)((m0 + wm + qm * 64 + mi * 16 + quad * 4 + r) & 2047);
#pragma unroll
                    for (int ni = 0; ni < 2; ni++) {
                        float sn, cs;
                        __sincosf(s * (ni ? fr1 : fr0), &sn, &cs);
                        float x1 = acc[qm][mi][0][ni][r];
                        float x2 = acc[qm][mi][1][ni][r];
                        acc[qm][mi][0][ni][r] = x1 * cs - x2 * sn;
                        acc[qm][mi][1][ni][r] = x2 * cs + x1 * sn;
                    }
                }
    }

#pragma unroll
    for (int qm = 0; qm < 2; qm++)
#pragma unroll
        for (int mi = 0; mi < 4; mi++)
#pragma unroll
            for (int qn = 0; qn < 2; qn++)
#pragma unroll
                for (int ni = 0; ni < 2; ni++)
#pragma unroll
                    for (int r = 0; r < 4; r++) {
                        int row = m0 + wm + qm * 64 + mi * 16 + quad * 4 + r;
                        int col = n0 + wn + qn * 32 + ni * 16 + l15;
                        float v = acc[qm][mi][qn][ni][r];
                        if (CF32) ((float*)Cv)[(long)row * ldc + col] = v;
                        else      ((short*)Cv)[(long)row * ldc + col] = f2bf(v);
                    }
}

// ================== 128x256 4-phase GEMM (full-chip variant, round-9 PASS) ==================
template <bool CF32>
__global__ __launch_bounds__(512, 2) void gemm_bt2(const short* __restrict__ A,
                                                   const short* __restrict__ Bt,
                                                   void* __restrict__ Cv,
                                                   int K, int lda, int ldb, int ldc) {
    __shared__ __align__(16) short Ab[2][8192];    // [buf][128*64]
    __shared__ __align__(16) short Bb[2][16384];   // [buf][256*64]

    const int tid = threadIdx.x;
    const int lane = tid & 63;
    const int wave = tid >> 6;
    const int quad = lane >> 4;
    const int l15 = lane & 15;

    const int nwg = gridDim.x * gridDim.y;
    int f = blockIdx.y * gridDim.x + blockIdx.x;
    if ((nwg & 7) == 0) f = (f & 7) * (nwg >> 3) + (f >> 3);
    const int m0 = (f / gridDim.x) * 128;
    const int n0 = (f % gridDim.x) * 256;

    const int wm = (wave >> 2) * 64;    // 0 or 64
    const int wn = (wave & 3) * 64;     // 0..192

    const int rsub = lane >> 3;
    const int sslot = (lane & 7) ^ rsub;
    const short* aS[2];
    const short* bS[4];
#pragma unroll
    for (int i = 0; i < 2; i++)
        aS[i] = A + (long)(m0 + wave * 16 + i * 8 + rsub) * lda + sslot * 8;
#pragma unroll
    for (int i = 0; i < 4; i++)
        bS[i] = Bt + (long)(n0 + wave * 32 + i * 8 + rsub) * ldb + sslot * 8;

    auto stageA = [&](int buf, int kt) {
        char* d = (char*)&Ab[buf][0] + wave * 2048;
        __builtin_amdgcn_global_load_lds((gp1_t)(aS[0] + (long)kt * 64), (lp3_t)d, 16, 0, 0);
        __builtin_amdgcn_global_load_lds((gp1_t)(aS[1] + (long)kt * 64), (lp3_t)(d + 1024), 16, 0, 0);
    };
    auto stageBh = [&](int buf, int h, int kt) {
        char* d = (char*)&Bb[buf][0] + wave * 4096 + h * 2048;
        __builtin_amdgcn_global_load_lds((gp1_t)(bS[2 * h] + (long)kt * 64), (lp3_t)d, 16, 0, 0);
        __builtin_amdgcn_global_load_lds((gp1_t)(bS[2 * h + 1] + (long)kt * 64), (lp3_t)(d + 1024), 16, 0, 0);
    };

    const int ks0 = (quad ^ (l15 & 7)) * 8;
    const int ks1 = ks0 ^ 32;

    f4v acc[4][2][2];   // [mi][qn][ni]
#pragma unroll
    for (int a = 0; a < 4; a++)
#pragma unroll
        for (int b = 0; b < 2; b++)
#pragma unroll
            for (int c = 0; c < 2; c++) acc[a][b][c] = (f4v){0.f, 0.f, 0.f, 0.f};

    const int NT = K >> 6;

    stageA(0, 0); stageBh(0, 0, 0); stageBh(0, 1, 0);
    stageA(1, 1); stageBh(1, 0, 1); stageBh(1, 1, 1);
    asm volatile("s_waitcnt vmcnt(6)" ::: "memory");
    __builtin_amdgcn_s_barrier();

    for (int t = 0; t < NT; ++t) {
        const short* Ac = &Ab[t & 1][0];
        const short* Bc = &Bb[t & 1][0];
        s8v af01[2][2], af23[2][2], bf0[2][2], bf1[2][2];

        // ---- phase 1
#pragma unroll
        for (int mi = 0; mi < 2; mi++) {
            const int row = wm + mi * 16 + l15;
            af01[mi][0] = *(const s8v*)&Ac[row * 64 + ks0];
            af01[mi][1] = *(const s8v*)&Ac[row * 64 + ks1];
        }
#pragma unroll
        for (int ni = 0; ni < 2; ni++) {
            const int row = wn + ni * 16 + l15;
            bf0[ni][0] = *(const s8v*)&Bc[row * 64 + ks0];
            bf0[ni][1] = *(const s8v*)&Bc[row * 64 + ks1];
        }
        __builtin_amdgcn_s_setprio(1);
#pragma unroll
        for (int mi = 0; mi < 2; mi++)
#pragma unroll
            for (int ni = 0; ni < 2; ni++) {
                acc[mi][0][ni] = __builtin_amdgcn_mfma_f32_16x16x32_bf16(af01[mi][0], bf0[ni][0], acc[mi][0][ni], 0, 0, 0);
                acc[mi][0][ni] = __builtin_amdgcn_mfma_f32_16x16x32_bf16(af01[mi][1], bf0[ni][1], acc[mi][0][ni], 0, 0, 0);
            }
        __builtin_amdgcn_s_setprio(0);
        __builtin_amdgcn_s_barrier();

        // ---- phase 2
#pragma unroll
        for (int ni = 0; ni < 2; ni++) {
            const int row = wn + 32 + ni * 16 + l15;
            bf1[ni][0] = *(const s8v*)&Bc[row * 64 + ks0];
            bf1[ni][1] = *(const s8v*)&Bc[row * 64 + ks1];
        }
        if (t + 2 < NT) stageBh(t & 1, 0, t + 2);
        __builtin_amdgcn_s_setprio(1);
#pragma unroll
        for (int mi = 0; mi < 2; mi++)
#pragma unroll
            for (int ni = 0; ni < 2; ni++) {
                acc[mi][1][ni] = __builtin_amdgcn_mfma_f32_16x16x32_bf16(af01[mi][0], bf1[ni][0], acc[mi][1][ni], 0, 0, 0);
                acc[mi][1][ni] = __builtin_amdgcn_mfma_f32_16x16x32_bf16(af01[mi][1], bf1[ni][1], acc[mi][1][ni], 0, 0, 0);
            }
        __builtin_amdgcn_s_setprio(0);
        __builtin_amdgcn_s_barrier();

        // ---- phase 3
#pragma unroll
        for (int mi = 0; mi < 2; mi++) {
            const int row = wm + 32 + mi * 16 + l15;
            af23[mi][0] = *(const s8v*)&Ac[row * 64 + ks0];
            af23[mi][1] = *(const s8v*)&Ac[row * 64 + ks1];
        }
        if (t + 2 < NT) stageBh(t & 1, 1, t + 2);
        __builtin_amdgcn_s_setprio(1);
#pragma unroll
        for (int mi = 0; mi < 2; mi++)
#pragma unroll
            for (int ni = 0; ni < 2; ni++) {
                acc[2 + mi][0][ni] = __builtin_amdgcn_mfma_f32_16x16x32_bf16(af23[mi][0], bf0[ni][0], acc[2 + mi][0][ni], 0, 0, 0);
                acc[2 + mi][0][ni] = __builtin_amdgcn_mfma_f32_16x16x32_bf16(af23[mi][1], bf0[ni][1], acc[2 + mi][0][ni], 0, 0, 0);
            }
        __builtin_amdgcn_s_setprio(0);
        __builtin_amdgcn_s_barrier();

        // ---- phase 4
        if (t + 2 < NT) stageA(t & 1, t + 2);
        __builtin_amdgcn_s_setprio(1);
#pragma unroll
        for (int mi = 0; mi < 2; mi++)
#pragma unroll
            for (int ni = 0; ni < 2; ni++) {
                acc[2 + mi][1][ni] = __builtin_amdgcn_mfma_f32_16x16x32_bf16(af23[mi][0], bf1[ni][0], acc[2 + mi][1][ni], 0, 0, 0);
                acc[2 + mi][1][ni] = __builtin_amdgcn_mfma_f32_16x16x32_bf16(af23[mi][1], bf1[ni][1], acc[2 + mi][1][ni], 0, 0, 0);
            }
        __builtin_amdgcn_s_setprio(0);
        if (t + 1 < NT) {
            if (t + 1 == NT - 1) asm volatile("s_waitcnt vmcnt(0)" ::: "memory");
            else                 asm volatile("s_waitcnt vmcnt(6)" ::: "memory");
            __builtin_amdgcn_s_barrier();
        }
    }

#pragma unroll
    for (int mi = 0; mi < 4; mi++)
#pragma unroll
        for (int qn = 0; qn < 2; qn++)
#pragma unroll
            for (int ni = 0; ni < 2; ni++)
#pragma unroll
                for (int r = 0; r < 4; r++) {
                    int row = m0 + wm + mi * 16 + quad * 4 + r;
                    int col = n0 + wn + qn * 32 + ni * 16 + l15;
                    float v = acc[mi][qn][ni][r];
                    if (CF32) ((float*)Cv)[(long)row * ldc + col] = v;
                    else      ((short*)Cv)[(long)row * ldc + col] = f2bf(v);
                }
}

// RoPE in-place on qkv cols [0,2560)  (fallback path only)
__global__ __launch_bounds__(256) void rope_kernel(short* __restrict__ qkv) {
    int tid = blockIdx.x * 256 + threadIdx.x;
    int p = tid % 1280;
    int row = tid / 1280;
    int head = p >> 5;
    int j = p & 31;
    int s = row & 2047;
    int c1 = head * 64 + j;
    float freq = exp2f(-(float)j * 0.4152410118609203f); // log2(10000)/32
    float ang = (float)s * freq;
    float sn, cs;
    __sincosf(ang, &sn, &cs);
    long base = (long)row * 3072;
    float x1 = bf2f(qkv[base + c1]);
    float x2 = bf2f(qkv[base + c1 + 32]);
    qkv[base + c1]      = f2bf(x1 * cs - x2 * sn);
    qkv[base + c1 + 32] = f2bf(x2 * cs + x1 * sn);
}

// V transpose with key-permutation pi applied per 64-key tile (round-10 PASS)
__global__ __launch_bounds__(256) void vtrans(const short* __restrict__ qkv,
                                              short* __restrict__ Vt_g) {
    __shared__ __align__(16) short tile[64 * 72];
    const int kt = blockIdx.x * 64;
    const int kvh = blockIdx.y;
    const int b = blockIdx.z;
    const int t = threadIdx.x;
#pragma unroll
    for (int cc = 0; cc < 2; cc++) {
        int ch = t + cc * 256;
        int key = ch >> 3, d0 = (ch & 7) * 8;
        s8v v = *(const s8v*)&qkv[(long)(b * 2048 + kt + key) * 3072 + 2560 + kvh * 64 + d0];
#pragma unroll
        for (int i = 0; i < 8; i++) tile[(d0 + i) * 72 + key] = v[i];
    }
    __syncthreads();
#pragma unroll
    for (int cc = 0; cc < 2; cc++) {
        int ch = t + cc * 256;
        int d = ch >> 3, c = ch & 7;
        int base1 = 32 * (c >> 2) + 4 * (c & 3);
        s4v lo = *(const s4v*)&tile[d * 72 + base1];
        s4v hi = *(const s4v*)&tile[d * 72 + base1 + 16];
        s8v w;
        w[0] = lo[0]; w[1] = lo[1]; w[2] = lo[2]; w[3] = lo[3];
        w[4] = hi[0]; w[5] = hi[1]; w[6] = hi[2]; w[7] = hi[3];
        *(s8v*)&Vt_g[(long)((b * 8 + kvh) * 64 + d) * 2048 + kt + c * 8] = w;
    }
}

// Flash attention v5 (round-10 PASS, 111.5 us): swapped QK^T, in-lane
// register PV A-fragments (pi_v-permuted V), VALU rs + LDS broadcast.
__global__ __launch_bounds__(256, 4) void attn5(short* __restrict__ qkv,
                                                const short* __restrict__ Vt_g) {
    __shared__ __align__(16) short KV[2][2][4096];   // [buf][K/V][64*64]
    __shared__ float rsb[4][32];

    const int tid = threadIdx.x;
    const int lane = tid & 63;
    const int wave = tid >> 6;
    const int quad = lane >> 4;
    const int l15 = lane & 15;

    int f = (blockIdx.z * 32 + blockIdx.y) * 16 + blockIdx.x;
    f = (f & 7) * 128 + (f >> 3);
    const int b = f >> 9;
    const int h = (f >> 4) & 31;
    const int kvh = h >> 2;
    const int q0 = (f & 15) * 128;

    const long kbase = ((long)b * 2048) * 3072 + 2048 + kvh * 64;
    const long vtbase = (long)(b * 8 + kvh) * 64 * 2048;

    const long qrow = (long)b * 2048 + q0 + wave * 32 + l15;
    const short* qp = qkv + qrow * 3072 + h * 64 + quad * 8;
    const s8v qf00 = *(const s8v*)(qp);
    const s8v qf01 = *(const s8v*)(qp + 32);
    const s8v qf10 = *(const s8v*)(qp + 16 * 3072);
    const s8v qf11 = *(const s8v*)(qp + 16 * 3072 + 32);

    const int rA = wave * 8 + (lane >> 3);
    const int sslot = (lane & 7) ^ (lane >> 3);
    const short* kA = qkv + kbase + (long)rA * 3072 + sslot * 8;
    const short* kB = kA + (long)32 * 3072;
    const short* vA = Vt_g + vtbase + (long)rA * 2048 + sslot * 8;
    const short* vB = vA + (long)32 * 2048;

    {
        char* kd = (char*)&KV[0][0][0] + wave * 1024;
        char* vd = (char*)&KV[0][1][0] + wave * 1024;
        __builtin_amdgcn_global_load_lds((gp1_t)kA, (lp3_t)kd, 16, 0, 0);
        __builtin_amdgcn_global_load_lds((gp1_t)kB, (lp3_t)(kd + 4096), 16, 0, 0);
        __builtin_amdgcn_global_load_lds((gp1_t)vA, (lp3_t)vd, 16, 0, 0);
        __builtin_amdgcn_global_load_lds((gp1_t)vB, (lp3_t)(vd + 4096), 16, 0, 0);
    }
    __syncthreads();

    const int ks0 = ((quad ^ (l15 & 7)) << 3);
    const int ks1 = ks0 ^ 32;

    f2v rs0v = (f2v){0.f, 0.f}, rs1v = (f2v){0.f, 0.f};
    f4v o0[4], o1[4];
#pragma unroll
    for (int ni = 0; ni < 4; ni++) { o0[ni] = (f4v){0.f, 0.f, 0.f, 0.f}; o1[ni] = (f4v){0.f, 0.f, 0.f, 0.f}; }

    for (int t = 0; t < 32; ++t) {
        const short* Kb = &KV[t & 1][0][0];
        const short* Vb = &KV[t & 1][1][0];

        if (t < 31) {
            const long ko = (long)(t + 1) * (64 * 3072);
            const long vo = (long)(t + 1) * 64;
            char* kd = (char*)&KV[(t + 1) & 1][0][0] + wave * 1024;
            char* vd = (char*)&KV[(t + 1) & 1][1][0] + wave * 1024;
            __builtin_amdgcn_global_load_lds((gp1_t)(kA + ko), (lp3_t)kd, 16, 0, 0);
            __builtin_amdgcn_global_load_lds((gp1_t)(kB + ko), (lp3_t)(kd + 4096), 16, 0, 0);
            __builtin_amdgcn_global_load_lds((gp1_t)(vA + vo), (lp3_t)vd, 16, 0, 0);
            __builtin_amdgcn_global_load_lds((gp1_t)(vB + vo), (lp3_t)(vd + 4096), 16, 0, 0);
        }

        // QK^T swapped: lane (quad,l15) reg r holds score-24 for
        // key = ni*16+quad*4+r, q = l15
        unsigned pk0[4][2], pk1[4][2];
#pragma unroll
        for (int ni = 0; ni < 4; ni++) {
            const int ro = (ni * 16 + l15) * 64;
            const s8v kf0 = *(const s8v*)&Kb[ro + ks0];
            const s8v kf1 = *(const s8v*)&Kb[ro + ks1];
            f4v a = (f4v){-24.f, -24.f, -24.f, -24.f};
            a = __builtin_amdgcn_mfma_f32_16x16x32_bf16(kf0, qf00, a, 0, 0, 0);
            a = __builtin_amdgcn_mfma_f32_16x16x32_bf16(kf1, qf01, a, 0, 0, 0);
            {
                float p0 = exp2f(a[0]);
                float p1 = exp2f(a[1]);
                float p2 = exp2f(a[2]);
                float p3 = exp2f(a[3]);
                rs0v += (f2v){p0, p1};
                rs0v += (f2v){p2, p3};
                pk0[ni][0] = cvt_pk_bf16(p0, p1);
                pk0[ni][1] = cvt_pk_bf16(p2, p3);
            }
            f4v c = (f4v){-24.f, -24.f, -24.f, -24.f};
            c = __builtin_amdgcn_mfma_f32_16x16x32_bf16(kf0, qf10, c, 0, 0, 0);
            c = __builtin_amdgcn_mfma_f32_16x16x32_bf16(kf1, qf11, c, 0, 0, 0);
            {
                float p0 = exp2f(c[0]);
                float p1 = exp2f(c[1]);
                float p2 = exp2f(c[2]);
                float p3 = exp2f(c[3]);
                rs1v += (f2v){p0, p1};
                rs1v += (f2v){p2, p3};
                pk1[ni][0] = cvt_pk_bf16(p0, p1);
                pk1[ni][1] = cvt_pk_bf16(p2, p3);
            }
        }

        // In-lane PV A-fragments (pi_v-permuted V)
        union PU { u4v u; s8v s; };
        PU pa0, pa1, pb0, pb1;
        pa0.u = (u4v){pk0[0][0], pk0[0][1], pk0[1][0], pk0[1][1]};
        pa1.u = (u4v){pk0[2][0], pk0[2][1], pk0[3][0], pk0[3][1]};
        pb0.u = (u4v){pk1[0][0], pk1[0][1], pk1[1][0], pk1[1][1]};
        pb1.u = (u4v){pk1[2][0], pk1[2][1], pk1[3][0], pk1[3][1]};

#pragma unroll
        for (int ni = 0; ni < 4; ni++) {
            const int ro = (ni * 16 + l15) * 64;
            const s8v vf0 = *(const s8v*)&Vb[ro + ks0];
            const s8v vf1 = *(const s8v*)&Vb[ro + ks1];
            o0[ni] = __builtin_amdgcn_mfma_f32_16x16x32_bf16(pa0.s, vf0, o0[ni], 0, 0, 0);
            o0[ni] = __builtin_amdgcn_mfma_f32_16x16x32_bf16(pa1.s, vf1, o0[ni], 0, 0, 0);
            o1[ni] = __builtin_amdgcn_mfma_f32_16x16x32_bf16(pb0.s, vf0, o1[ni], 0, 0, 0);
            o1[ni] = __builtin_amdgcn_mfma_f32_16x16x32_bf16(pb1.s, vf1, o1[ni], 0, 0, 0);
        }
        __syncthreads();
    }

    float rs0 = rs0v[0] + rs0v[1];
    float rs1 = rs1v[0] + rs1v[1];
    rs0 += __shfl_xor(rs0, 16); rs0 += __shfl_xor(rs0, 32);
    rs1 += __shfl_xor(rs1, 16); rs1 += __shfl_xor(rs1, 32);
    if (quad == 0) { rsb[wave][l15] = rs0; rsb[wave][16 + l15] = rs1; }
    __syncthreads();

#pragma unroll
    for (int r = 0; r < 4; r++) {
        const float i0 = 1.0f / rsb[wave][quad * 4 + r];
        const float i1 = 1.0f / rsb[wave][16 + quad * 4 + r];
        const long ob0 = ((long)b * 2048 + q0 + wave * 32 + quad * 4 + r) * 3072 + h * 64;
        const long ob1 = ob0 + 16 * 3072;
#pragma unroll
        for (int ni = 0; ni < 4; ni++) {
            qkv[ob0 + ni * 16 + l15] = f2bf(o0[ni][r] * i0);
            qkv[ob1 + ni * 16 + l15] = f2bf(o1[ni][r] * i1);
        }
    }
}

// ======================= FALLBACK PATH (round-6, known-PASS) =======================

template <bool AF32, bool CF32>
__global__ __launch_bounds__(256) void gemm_bn(const void* __restrict__ Av,
                                               const float* __restrict__ B,
                                               void* __restrict__ Cv,
                                               int K, int N, int lda, int ldc) {
    __shared__ __align__(16) short As[128 * 40];
    __shared__ __align__(16) short Bs[128 * 40];
    const int tid = threadIdx.x;
    const int lane = tid & 63;
    const int wave = tid >> 6;
    const int quad = lane >> 4;
    const int l15 = lane & 15;
    const int m0 = blockIdx.y * 128;
    const int n0 = blockIdx.x * 128;
    const int wm = (wave & 1) * 64;
    const int wn = (wave >> 1) * 64;

    f4v acc[4][4];
#pragma unroll
    for (int i = 0; i < 4; i++)
#pragma unroll
        for (int j = 0; j < 4; j++) acc[i][j] = (f4v){0.f, 0.f, 0.f, 0.f};

    const int ar0 = tid >> 2, akc0 = (tid & 3) * 8;
    const int ar1 = (tid + 256) >> 2, akc1 = ((tid + 256) & 3) * 8;
    const int bk0 = tid >> 4, bnc0 = (tid & 15) * 8;
    const int bk1 = (tid + 256) >> 4, bnc1 = ((tid + 256) & 15) * 8;

    for (int k0 = 0; k0 < K; k0 += 32) {
        __syncthreads();
        if (AF32) {
            const float* A = (const float*)Av;
            *(s8v*)(&As[ar0 * 40 + akc0]) = cvt8(&A[(long)(m0 + ar0) * lda + k0 + akc0]);
            *(s8v*)(&As[ar1 * 40 + akc1]) = cvt8(&A[(long)(m0 + ar1) * lda + k0 + akc1]);
        } else {
            const short* A = (const short*)Av;
            *(s8v*)(&As[ar0 * 40 + akc0]) = *(const s8v*)(&A[(long)(m0 + ar0) * lda + k0 + akc0]);
            *(s8v*)(&As[ar1 * 40 + akc1]) = *(const s8v*)(&A[(long)(m0 + ar1) * lda + k0 + akc1]);
        }
        s8v b0 = cvt8(&B[(long)(k0 + bk0) * N + n0 + bnc0]);
        s8v b1 = cvt8(&B[(long)(k0 + bk1) * N + n0 + bnc1]);
#pragma unroll
        for (int i = 0; i < 8; i++) Bs[(bnc0 + i) * 40 + bk0] = b0[i];
#pragma unroll
        for (int i = 0; i < 8; i++) Bs[(bnc1 + i) * 40 + bk1] = b1[i];
        __syncthreads();
        s8v af[4], bfr[4];
#pragma unroll
        for (int mi = 0; mi < 4; mi++)
            af[mi] = *(const s8v*)(&As[(wm + mi * 16 + l15) * 40 + quad * 8]);
#pragma unroll
        for (int ni = 0; ni < 4; ni++)
            bfr[ni] = *(const s8v*)(&Bs[(wn + ni * 16 + l15) * 40 + quad * 8]);
#pragma unroll
        for (int mi = 0; mi < 4; mi++)
#pragma unroll
            for (int ni = 0; ni < 4; ni++)
                acc[mi][ni] = __builtin_amdgcn_mfma_f32_16x16x32_bf16(af[mi], bfr[ni], acc[mi][ni], 0, 0, 0);
    }
#pragma unroll
    for (int mi = 0; mi < 4; mi++)
#pragma unroll
        for (int ni = 0; ni < 4; ni++)
#pragma unroll
            for (int r = 0; r < 4; r++) {
                int row = m0 + wm + mi * 16 + quad * 4 + r;
                int col = n0 + wn + ni * 16 + l15;
                if (CF32) ((float*)Cv)[(long)row * ldc + col] = acc[mi][ni][r];
                else      ((short*)Cv)[(long)row * ldc + col] = f2bf(acc[mi][ni][r]);
            }
}

__global__ __launch_bounds__(256) void attn_kernel(short* __restrict__ qkv) {
    __shared__ __align__(16) short Qs[64 * 72];
    __shared__ __align__(16) short Ks[64 * 72];
    __shared__ __align__(16) short Vt[64 * 72];
    __shared__ __align__(16) short Ps[4][16 * 72];

    const int tid = threadIdx.x;
    const int lane = tid & 63;
    const int wave = tid >> 6;
    const int quad = lane >> 4;
    const int l15 = lane & 15;
    const int b = blockIdx.z;
    const int h = blockIdx.y;
    const int kvh = h >> 2;
    const int q0 = blockIdx.x * 64;

    const long qbase = ((long)b * 2048 + q0) * 3072 + h * 64;
    const long kbase = ((long)b * 2048) * 3072 + 2048 + kvh * 64;
    const long vbase = kbase + 512;

#pragma unroll
    for (int cc = 0; cc < 2; cc++) {
        int ch = tid + cc * 256;
        int r = ch >> 3, d0 = (ch & 7) * 8;
        *(s8v*)(&Qs[r * 72 + d0]) = *(const s8v*)(&qkv[qbase + (long)r * 3072 + d0]);
    }
    __syncthreads();
    s8v qf[2];
    qf[0] = *(const s8v*)(&Qs[(wave * 16 + l15) * 72 + quad * 8]);
    qf[1] = *(const s8v*)(&Qs[(wave * 16 + l15) * 72 + 32 + quad * 8]);

    float m_i[4], l_i[4];
    f4v o[4];
#pragma unroll
    for (int r = 0; r < 4; r++) { m_i[r] = -1e30f; l_i[r] = 0.0f; }
#pragma unroll
    for (int ni = 0; ni < 4; ni++) o[ni] = (f4v){0.f, 0.f, 0.f, 0.f};

    for (int kt = 0; kt < 2048; kt += 64) {
        __syncthreads();
#pragma unroll
        for (int cc = 0; cc < 2; cc++) {
            int ch = tid + cc * 256;
            int r = ch >> 3, d0 = (ch & 7) * 8;
            *(s8v*)(&Ks[r * 72 + d0]) = *(const s8v*)(&qkv[kbase + (long)(kt + r) * 3072 + d0]);
            s8v v = *(const s8v*)(&qkv[vbase + (long)(kt + r) * 3072 + d0]);
            int g = d0 >> 3;
            int chn = ((r >> 3) ^ g) * 8 + (r & 7);
#pragma unroll
            for (int i = 0; i < 8; i++) Vt[(d0 + i) * 72 + chn] = v[i];
        }
        __syncthreads();

        f4v sc[4];
#pragma unroll
        for (int ni = 0; ni < 4; ni++) {
            s8v kf0 = *(const s8v*)(&Ks[(ni * 16 + l15) * 72 + quad * 8]);
            s8v kf1 = *(const s8v*)(&Ks[(ni * 16 + l15) * 72 + 32 + quad * 8]);
            f4v a = (f4v){0.f, 0.f, 0.f, 0.f};
            a = __builtin_amdgcn_mfma_f32_16x16x32_bf16(qf[0], kf0, a, 0, 0, 0);
            a = __builtin_amdgcn_mfma_f32_16x16x32_bf16(qf[1], kf1, a, 0, 0, 0);
            sc[ni] = a * 0.125f;
        }
        float alpha[4], rs[4];
#pragma unroll
        for (int r = 0; r < 4; r++) {
            float v = fmaxf(fmaxf(sc[0][r], sc[1][r]), fmaxf(sc[2][r], sc[3][r]));
            v = fmaxf(v, __shfl_xor(v, 1));
            v = fmaxf(v, __shfl_xor(v, 2));
            v = fmaxf(v, __shfl_xor(v, 4));
            v = fmaxf(v, __shfl_xor(v, 8));
            float mn = fmaxf(m_i[r], v);
            alpha[r] = __expf(m_i[r] - mn);
            m_i[r] = mn;
            rs[r] = 0.f;
        }
#pragma unroll
        for (int ni = 0; ni < 4; ni++)
#pragma unroll
            for (int r = 0; r < 4; r++) {
                float pv = __expf(sc[ni][r] - m_i[r]);
                sc[ni][r] = pv;
                rs[r] += pv;
            }
#pragma unroll
        for (int r = 0; r < 4; r++) {
            float v = rs[r];
            v += __shfl_xor(v, 1);
            v += __shfl_xor(v, 2);
            v += __shfl_xor(v, 4);
            v += __shfl_xor(v, 8);
            l_i[r] = l_i[r] * alpha[r] + v;
        }
#pragma unroll
        for (int ni = 0; ni < 4; ni++)
#pragma unroll
            for (int r = 0; r < 4; r++) {
                int row = quad * 4 + r;
                int key = ni * 16 + l15;
                int chn = ((key >> 3) ^ (row >> 3)) * 8 + (key & 7);
                Ps[wave][row * 72 + chn] = f2bf(sc[ni][r]);
            }
        __syncthreads();
#pragma unroll
        for (int ni = 0; ni < 4; ni++) {
            f4v t = o[ni];
            t[0] *= alpha[0]; t[1] *= alpha[1]; t[2] *= alpha[2]; t[3] *= alpha[3];
            o[ni] = t;
        }
        s8v pf0 = *(const s8v*)(&Ps[wave][l15 * 72 + ((quad ^ (l15 >> 3)) * 8)]);
        s8v pf1 = *(const s8v*)(&Ps[wave][l15 * 72 + (((4 + quad) ^ (l15 >> 3)) * 8)]);
#pragma unroll
        for (int ni = 0; ni < 4; ni++) {
            int d = ni * 16 + l15;
            s8v vf0 = *(const s8v*)(&Vt[d * 72 + ((quad ^ (d >> 3)) * 8)]);
            s8v vf1 = *(const s8v*)(&Vt[d * 72 + (((4 + quad) ^ (d >> 3)) * 8)]);
            o[ni] = __builtin_amdgcn_mfma_f32_16x16x32_bf16(pf0, vf0, o[ni], 0, 0, 0);
            o[ni] = __builtin_amdgcn_mfma_f32_16x16x32_bf16(pf1, vf1, o[ni], 0, 0, 0);
        }
    }
#pragma unroll
    for (int r = 0; r < 4; r++) {
        float inv = 1.0f / l_i[r];
        int srow = q0 + wave * 16 + quad * 4 + r;
        long obase = ((long)b * 2048 + srow) * 3072 + h * 64;
#pragma unroll
        for (int ni = 0; ni < 4; ni++)
            qkv[obase + ni * 16 + l15] = f2bf(o[ni][r] * inv);
    }
}

extern "C" void kernel_launch(void* const* d_in, const int* in_sizes, int n_in,
                              void* d_out, int out_size, void* d_ws, size_t ws_size,
                              hipStream_t stream) {
    (void)in_sizes; (void)n_in; (void)out_size;
    const float* x  = (const float*)d_in[0];
    const float* Wq = (const float*)d_in[1];
    const float* Wk = (const float*)d_in[2];
    const float* Wv = (const float*)d_in[3];
    const float* Wo = (const float*)d_in[4];

    const size_t need = 67108864ULL; // 64 MiB
    if (ws_size >= need) {
        short* xb    = (short*)d_ws;              // 4096x2048
        short* Wqkvt = xb + 8388608;              // 3072x2048
        short* Wot   = Wqkvt + 6291456;           // 2048x2048
        short* qkv   = Wot + 4194304;             // 4096x3072
        short* Vt_g  = qkv + 12582912;            // 16x64x2048

        prep<<<6656, 256, 0, stream>>>(x, Wq, Wk, Wv, Wo, xb, Wqkvt, Wot);
        gemm_bt8<false, true><<<dim3(12, 16), 512, 0, stream>>>(xb, Wqkvt, qkv, 2048, 2048, 2048, 3072);
        vtrans<<<dim3(32, 8, 2), 256, 0, stream>>>(qkv, Vt_g);
        attn5<<<dim3(16, 32, 2), 256, 0, stream>>>(qkv, Vt_g);
        gemm_bt2<true><<<dim3(8, 32), 512, 0, stream>>>(qkv, Wot, d_out, 2048, 3072, 2048, 2048);
    } else {
        short* qkv = (short*)d_ws;
        gemm_bn<true, false><<<dim3(16, 32), 256, 0, stream>>>(x, Wq, qkv,        2048, 2048, 2048, 3072);
        gemm_bn<true, false><<<dim3(4, 32), 256, 0, stream>>>(x, Wk, qkv + 2048, 2048,  512, 2048, 3072);
        gemm_bn<true, false><<<dim3(4, 32), 256, 0, stream>>>(x, Wv, qkv + 2560, 2048,  512, 2048, 3072);
        rope_kernel<<<dim3(20480), 256, 0, stream>>>(qkv);
        attn_kernel<<<dim3(32, 32, 2), 256, 0, stream>>>(qkv);
        gemm_bn<false, true><<<dim3(16, 32), 256, 0, stream>>>(qkv, Wo, d_out, 2048, 2048, 3072, 2048);
    }
}